// Round 1
// baseline (1269.941 us; speedup 1.0000x reference)
//
#include <hip/hip_runtime.h>
#include <stdint.h>

#define NN 32768            // nodes
#define HID 512
#define AS1 __attribute__((address_space(1)))
#define AS3 __attribute__((address_space(3)))

typedef _Float16 h8 __attribute__((ext_vector_type(8)));
typedef _Float16 h2 __attribute__((ext_vector_type(2)));
typedef float f4 __attribute__((ext_vector_type(4)));

__device__ __forceinline__ void gload_lds16(const _Float16* g, _Float16* l) {
    // async global->LDS, 16B per lane; LDS dest = wave-uniform base + lane*16
    __builtin_amdgcn_global_load_lds((AS1 void*)(g), (AS3 void*)(l), 16, 0, 0);
}

// ---------------- setup kernels ----------------

// transpose+cast: src fp32 [K,N] row-major -> dst fp16 [N,Kp], zero-padded K->Kp
__global__ void conv_t(const float* __restrict__ src, _Float16* __restrict__ dst,
                       int K, int N, int Kp) {
    int idx = blockIdx.x * 256 + threadIdx.x;
    if (idx >= N * Kp) return;
    int n = idx / Kp, k = idx - n * Kp;
    dst[idx] = (k < K) ? (_Float16)src[(size_t)k * N + n] : (_Float16)0.f;
}

// pad+cast features: src fp32 [NN,F] -> dst fp16 [NN,Kp]
__global__ void pad_x(const float* __restrict__ src, _Float16* __restrict__ dst,
                      int F, int Kp, int total) {
    int idx = blockIdx.x * 256 + threadIdx.x;
    if (idx >= total) return;
    int i = idx / Kp, j = idx - i * Kp;
    dst[idx] = (j < F) ? (_Float16)src[(size_t)i * F + j] : (_Float16)0.f;
}

__global__ void init_deg(int* deg) { deg[blockIdx.x * 256 + threadIdx.x] = 1; } // self loop

__global__ void count_edges(const int* __restrict__ col, int E, int* deg) {
    int e = blockIdx.x * 256 + threadIdx.x;
    if (e < E) atomicAdd(&deg[col[e]], 1);
}

__global__ void compute_dis(const int* __restrict__ deg, float* __restrict__ dis) {
    int i = blockIdx.x * 256 + threadIdx.x;
    dis[i] = rsqrtf((float)deg[i]);
}

// exclusive scan of (deg-1) over exactly 32768 nodes; single block, 1024 thr x 32 elems
__global__ void scan_offsets(const int* __restrict__ deg, int* __restrict__ offs,
                             int* __restrict__ cur) {
    __shared__ int part[1024];
    int t = threadIdx.x, base = t * 32;
    int loc[32], sum = 0;
    for (int j = 0; j < 32; ++j) { loc[j] = sum; sum += deg[base + j] - 1; }
    part[t] = sum;
    __syncthreads();
    for (int o = 1; o < 1024; o <<= 1) {
        int v = (t >= o) ? part[t - o] : 0;
        __syncthreads();
        part[t] += v;
        __syncthreads();
    }
    int pre = (t == 0) ? 0 : part[t - 1];
    for (int j = 0; j < 32; ++j) { int x = pre + loc[j]; offs[base + j] = x; cur[base + j] = x; }
    if (t == 1023) offs[NN] = part[1023];
}

__global__ void scatter_edges(const int* __restrict__ row, const int* __restrict__ col,
                              int E, int* cur, int* __restrict__ srow) {
    int e = blockIdx.x * 256 + threadIdx.x;
    if (e < E) { int p = atomicAdd(&cur[col[e]], 1); srow[p] = row[e]; }
}

// ---------------- aggregation: support = 0.8*(D^-1/2 (A+I) D^-1/2 prev) + 0.2*h0 ----------------
// one block per node, 256 thr x 2 fp16 features
__global__ void agg_kernel(const _Float16* __restrict__ prev, const _Float16* __restrict__ h0,
                           const float* __restrict__ dis, const int* __restrict__ offs,
                           const int* __restrict__ srow, _Float16* __restrict__ sup) {
    int i = blockIdx.x, t = threadIdx.x;
    size_t base = (size_t)i * HID + t * 2;
    int s0 = offs[i], s1 = offs[i + 1];
    float a0 = 0.f, a1 = 0.f;
    for (int e = s0; e < s1; ++e) {
        int r = srow[e];
        float s = dis[r];
        h2 v = *(const h2*)&prev[(size_t)r * HID + t * 2];
        a0 += s * (float)v[0];
        a1 += s * (float)v[1];
    }
    float si = dis[i];
    h2 pv = *(const h2*)&prev[base];
    h2 hv = *(const h2*)&h0[base];
    float r0 = 0.8f * si * (a0 + si * (float)pv[0]) + 0.2f * (float)hv[0];
    float r1 = 0.8f * si * (a1 + si * (float)pv[1]) + 0.2f * (float)hv[1];
    h2 o; o[0] = (_Float16)r0; o[1] = (_Float16)r1;
    *(h2*)&sup[base] = o;
}

// ---------------- MFMA GEMM: C[M,N] = A[M,K] @ B[K,N], B given transposed BT[N,K] ----------------
// 128x128 tile, BK=64, 4 waves in 2x2 grid, 4x4 16x16x32 f16 MFMA frags per wave (m97 structure)
enum { EPI_RELU2 = 0, EPI_BIAS = 1, EPI_GCN = 2 };

template <int EPI>
__global__ __launch_bounds__(256) void gemm_k(
    const _Float16* __restrict__ A, const _Float16* __restrict__ BT, int K,
    _Float16* __restrict__ C, int ldc, int coff, const float* __restrict__ bias,
    _Float16* __restrict__ C2, const _Float16* __restrict__ S, _Float16* __restrict__ P) {
    // LDS layout: [k8][row][8 halfs] so global_load_lds lane order == fragment-read order
    __shared__ _Float16 lA[8 * 128 * 8];
    __shared__ _Float16 lB[8 * 128 * 8];
    const int tid = threadIdx.x;
    const int wave = tid >> 6, lane = tid & 63;
    const int row0 = blockIdx.x * 128, col0 = blockIdx.y * 128;
    const int wm = wave & 1, wn = wave >> 1;
    f4 acc[4][4] = {};
    const int nk = K >> 6;
    for (int kt = 0; kt < nk; ++kt) {
        const int k0 = kt << 6;
        __syncthreads();  // prior iter's ds_reads done before overwrite
        #pragma unroll
        for (int q = 0; q < 4; ++q) {
            const int c = wave * 4 + q;
            const int k8 = c & 7, rh = c >> 3;
            gload_lds16(A + (size_t)(row0 + rh * 64 + lane) * K + k0 + k8 * 8,
                        &lA[(k8 * 128 + rh * 64) * 8]);
            gload_lds16(BT + (size_t)(col0 + rh * 64 + lane) * K + k0 + k8 * 8,
                        &lB[(k8 * 128 + rh * 64) * 8]);
        }
        __syncthreads();  // compiler drains vmcnt before barrier -> LDS valid
        #pragma unroll
        for (int s = 0; s < 2; ++s) {
            h8 af[4], bf[4];
            const int kq = s * 4 + (lane >> 4);
            #pragma unroll
            for (int t = 0; t < 4; ++t) {
                af[t] = *(const h8*)&lA[(kq * 128 + wm * 64 + t * 16 + (lane & 15)) * 8];
                bf[t] = *(const h8*)&lB[(kq * 128 + wn * 64 + t * 16 + (lane & 15)) * 8];
            }
            #pragma unroll
            for (int rt = 0; rt < 4; ++rt)
                #pragma unroll
                for (int ct = 0; ct < 4; ++ct)
                    acc[rt][ct] = __builtin_amdgcn_mfma_f32_16x16x32_f16(af[rt], bf[ct], acc[rt][ct], 0, 0, 0);
        }
    }
    // epilogue: C/D frag mapping col=lane&15, row=(lane>>4)*4+r (m89-verified, dtype-indep)
    #pragma unroll
    for (int rt = 0; rt < 4; ++rt) {
        #pragma unroll
        for (int ct = 0; ct < 4; ++ct) {
            const int col = col0 + wn * 64 + ct * 16 + (lane & 15);
            #pragma unroll
            for (int r = 0; r < 4; ++r) {
                const int row = row0 + wm * 64 + rt * 16 + (lane >> 4) * 4 + r;
                float v = acc[rt][ct][r];
                if (EPI == EPI_RELU2) {
                    v = fmaxf(v + bias[col], 0.f);
                    C[(size_t)row * ldc + col] = (_Float16)v;
                    if (C2) C2[(size_t)row * ldc + col] = (_Float16)v;
                } else if (EPI == EPI_BIAS) {
                    C[(size_t)row * ldc + coff + col] = (_Float16)(v + bias[col]);
                } else {  // EPI_GCN: prev = relu(support + support@W) + prev, in place
                    const size_t idx = (size_t)row * HID + col;
                    float nv = fmaxf((float)S[idx] + v, 0.f) + (float)P[idx];
                    P[idx] = (_Float16)nv;
                }
            }
        }
    }
}

// ---------------- final projection: out[i] = x2[i,:512] . w_o + b_o (fp32 out) ----------------
__global__ void final_dot(const _Float16* __restrict__ x2, const float* __restrict__ w,
                          const float* __restrict__ b, float* __restrict__ out) {
    int wave = threadIdx.x >> 6, lane = threadIdx.x & 63;
    int row = blockIdx.x * 4 + wave;
    h8 v = *(const h8*)&x2[(size_t)row * 512 + lane * 8];
    float s = 0.f;
    #pragma unroll
    for (int j = 0; j < 8; ++j) s += (float)v[j] * w[lane * 8 + j];
    #pragma unroll
    for (int off = 32; off > 0; off >>= 1) s += __shfl_down(s, off);
    if (lane == 0) out[row] = s + b[0];
}

// ---------------- host orchestration ----------------
extern "C" void kernel_launch(void* const* d_in, const int* in_sizes, int n_in,
                              void* d_out, int out_size, void* d_ws, size_t ws_size,
                              hipStream_t stream) {
    const float* mol_x   = (const float*)d_in[0];
    const int*   mol_ei  = (const int*)d_in[1];
    const float* pro_x   = (const float*)d_in[2];
    const int*   pro_ei  = (const int*)d_in[3];
    const float* mol_win = (const float*)d_in[4];
    const float* mol_bin = (const float*)d_in[5];
    const float* mol_ws  = (const float*)d_in[6];
    const float* mol_wo  = (const float*)d_in[7];
    const float* mol_bo  = (const float*)d_in[8];
    const float* pro_win = (const float*)d_in[9];
    const float* pro_bin = (const float*)d_in[10];
    const float* pro_ws  = (const float*)d_in[11];
    const float* pro_wo  = (const float*)d_in[12];
    const float* pro_bo  = (const float*)d_in[13];
    const float* w_fc1   = (const float*)d_in[14];
    const float* b_fc1   = (const float*)d_in[15];
    const float* w_fc2   = (const float*)d_in[16];
    const float* b_fc2   = (const float*)d_in[17];
    const float* w_o     = (const float*)d_in[18];
    const float* b_o     = (const float*)d_in[19];
    const int E_MOL = 131072, E_PRO = 196608;

    char* wsb = (char*)d_ws;
    size_t off = 0;
    auto alloc = [&](size_t bytes) -> void* {
        off = (off + 255) & ~(size_t)255;
        void* p = wsb + off;
        off += bytes;
        return p;
    };
    int*      deg   = (int*)alloc(NN * 4);
    float*    dis   = (float*)alloc(NN * 4);
    int*      offs  = (int*)alloc((NN + 1) * 4);
    int*      cur   = (int*)alloc(NN * 4);
    int*      srow  = (int*)alloc((size_t)E_PRO * 4);
    _Float16* xpad  = (_Float16*)alloc((size_t)NN * 128 * 2);
    _Float16* winT  = (_Float16*)alloc(512 * 128 * 2);
    _Float16* wsT   = (_Float16*)alloc((size_t)3 * 512 * 512 * 2);
    _Float16* woutT = (_Float16*)alloc(128 * 512 * 2);
    _Float16* fc1T  = (_Float16*)alloc(1024 * 256 * 2);
    _Float16* fc2T  = (_Float16*)alloc((size_t)512 * 1024 * 2);
    _Float16* h0    = (_Float16*)alloc((size_t)NN * HID * 2);
    _Float16* prev  = (_Float16*)alloc((size_t)NN * HID * 2);  // contiguous after h0
    _Float16* sup   = (_Float16*)alloc((size_t)NN * HID * 2);
    _Float16* xc    = (_Float16*)alloc((size_t)NN * 256 * 2);
    _Float16* x1 = h0;   // [NN,1024] aliases h0+prev (both free after branches)
    _Float16* x2 = sup;  // [NN,512]

    // MLP weights (once)
    conv_t<<<(1024 * 256 + 255) / 256, 256, 0, stream>>>(w_fc1, fc1T, 256, 1024, 256);
    conv_t<<<(512 * 1024 + 255) / 256, 256, 0, stream>>>(w_fc2, fc2T, 1024, 512, 1024);

    auto run_branch = [&](const float* x, int F, const int* ei, int E,
                          const float* win, const float* bin, const float* ws3,
                          const float* wo, const float* bo, int coff) {
        // weights
        conv_t<<<(512 * 128 + 255) / 256, 256, 0, stream>>>(win, winT, F, 512, 128);
        for (int l = 0; l < 3; ++l)
            conv_t<<<(512 * 512 + 255) / 256, 256, 0, stream>>>(
                ws3 + (size_t)l * 512 * 512, wsT + (size_t)l * 512 * 512, 512, 512, 512);
        conv_t<<<(128 * 512 + 255) / 256, 256, 0, stream>>>(wo, woutT, 512, 128, 512);
        pad_x<<<(NN * 128 + 255) / 256, 256, 0, stream>>>(x, xpad, F, 128, NN * 128);
        // gcn_norm + CSR (sorted by col)
        init_deg<<<NN / 256, 256, 0, stream>>>(deg);
        count_edges<<<(E + 255) / 256, 256, 0, stream>>>(ei + E, E, deg);
        compute_dis<<<NN / 256, 256, 0, stream>>>(deg, dis);
        scan_offsets<<<1, 1024, 0, stream>>>(deg, offs, cur);
        scatter_edges<<<(E + 255) / 256, 256, 0, stream>>>(ei, ei + E, E, cur, srow);
        // h = relu(x@Win + b); h0 = prev = h
        gemm_k<EPI_RELU2><<<dim3(256, 4), 256, 0, stream>>>(
            xpad, winT, 128, h0, HID, 0, bin, prev, nullptr, nullptr);
        for (int l = 0; l < 3; ++l) {
            agg_kernel<<<NN, 256, 0, stream>>>(prev, h0, dis, offs, srow, sup);
            gemm_k<EPI_GCN><<<dim3(256, 4), 256, 0, stream>>>(
                sup, wsT + (size_t)l * 512 * 512, 512, nullptr, HID, 0, nullptr, nullptr, sup, prev);
        }
        // branch out -> xc[:, coff:coff+128]
        gemm_k<EPI_BIAS><<<dim3(256, 1), 256, 0, stream>>>(
            prev, woutT, 512, xc, 256, coff, bo, nullptr, nullptr, nullptr);
    };

    run_branch(mol_x, 78, mol_ei, E_MOL, mol_win, mol_bin, mol_ws, mol_wo, mol_bo, 0);
    run_branch(pro_x, 54, pro_ei, E_PRO, pro_win, pro_bin, pro_ws, pro_wo, pro_bo, 128);

    // MLP head
    gemm_k<EPI_RELU2><<<dim3(256, 8), 256, 0, stream>>>(
        xc, fc1T, 256, x1, 1024, 0, b_fc1, nullptr, nullptr, nullptr);
    gemm_k<EPI_RELU2><<<dim3(256, 4), 256, 0, stream>>>(
        x1, fc2T, 1024, x2, 512, 0, b_fc2, nullptr, nullptr, nullptr);
    final_dot<<<NN / 4, 256, 0, stream>>>(x2, w_o, b_o, (float*)d_out);
    (void)in_sizes; (void)n_in; (void)out_size; (void)ws_size;
}

// Round 2
// 1081.060 us; speedup vs baseline: 1.1747x; 1.1747x over previous
//
#include <hip/hip_runtime.h>
#include <stdint.h>

#define NN 32768            // nodes
#define HID 512
#define EM 131072           // mol edges
#define EP 196608           // pro edges
#define AS1 __attribute__((address_space(1)))
#define AS3 __attribute__((address_space(3)))

typedef _Float16 h8 __attribute__((ext_vector_type(8)));
typedef _Float16 h2 __attribute__((ext_vector_type(2)));
typedef float f4 __attribute__((ext_vector_type(4)));

__device__ __forceinline__ void gload_lds16(const _Float16* g, _Float16* l) {
    __builtin_amdgcn_global_load_lds((AS1 void*)(g), (AS3 void*)(l), 16, 0, 0);
}

// ---------------- fused weight conversion: 12 transpose+cast jobs in one launch ----------------
struct ConvJobs {
    const float* src[12];
    _Float16* dst[12];
    int K[12], N[12], Kp[12];
    int blk0[13];   // cumulative block starts
};

__global__ void conv_all(ConvJobs j) {
    int blk = blockIdx.x, job = 0;
    while (blk >= j.blk0[job + 1]) ++job;
    int idx = (blk - j.blk0[job]) * 256 + threadIdx.x;
    int Kp = j.Kp[job], N = j.N[job], K = j.K[job];
    if (idx >= N * Kp) return;
    int n = idx / Kp, k = idx - n * Kp;
    j.dst[job][idx] = (k < K) ? (_Float16)j.src[job][(size_t)k * N + n] : (_Float16)0.f;
}

// pad+cast features fp32 [NN,F] -> fp16 [NN,128]; z selects branch (combined mode)
__global__ void pad_x2(const float* s0, const float* s1, int F0, int F1, _Float16* dstb) {
    int z = blockIdx.z;
    const float* src = z ? s1 : s0;
    int F = z ? F1 : F0;
    _Float16* dst = dstb + (size_t)z * NN * 128;
    int idx = blockIdx.x * 256 + threadIdx.x;
    int i = idx >> 7, jj = idx & 127;
    dst[idx] = (jj < F) ? (_Float16)src[(size_t)i * F + jj] : (_Float16)0.f;
}

// ---------------- CSR build (both branches always, meta arrays are [2][...]) ----------------
__global__ void init_deg(int* deg) {
    deg[(size_t)blockIdx.z * NN + blockIdx.x * 256 + threadIdx.x] = 1;  // self loop
}

__global__ void count_edges2(const int* c0, int E0, const int* c1, int E1, int* deg) {
    int i = blockIdx.x * 256 + threadIdx.x;
    if (i < E0) atomicAdd(&deg[c0[i]], 1);
    else { i -= E0; if (i < E1) atomicAdd(&deg[NN + c1[i]], 1); }
}

__global__ void compute_dis(const int* deg, float* dis) {
    int i = blockIdx.z * NN + blockIdx.x * 256 + threadIdx.x;
    dis[i] = rsqrtf((float)deg[i]);
}

// exclusive scan of (deg-1); one block per branch (blockIdx.z)
__global__ void scan_offsets(const int* degb, int* offsb, int* curb) {
    const int* deg = degb + blockIdx.z * NN;
    int* offs = offsb + blockIdx.z * (NN + 1);
    int* cur = curb + blockIdx.z * NN;
    __shared__ int part[1024];
    int t = threadIdx.x, base = t * 32;
    int loc[32], sum = 0;
    for (int j = 0; j < 32; ++j) { loc[j] = sum; sum += deg[base + j] - 1; }
    part[t] = sum;
    __syncthreads();
    for (int o = 1; o < 1024; o <<= 1) {
        int v = (t >= o) ? part[t - o] : 0;
        __syncthreads();
        part[t] += v;
        __syncthreads();
    }
    int pre = (t == 0) ? 0 : part[t - 1];
    for (int j = 0; j < 32; ++j) { int x = pre + loc[j]; offs[base + j] = x; cur[base + j] = x; }
    if (t == 1023) offs[NN] = part[1023];
}

__global__ void scatter2(const int* r0, const int* c0, int E0,
                         const int* r1, const int* c1, int E1,
                         int* cur, int* s0, int* s1) {
    int i = blockIdx.x * 256 + threadIdx.x;
    if (i < E0) { int p = atomicAdd(&cur[c0[i]], 1); s0[p] = r0[i]; }
    else { i -= E0; if (i < E1) { int p = atomicAdd(&cur[NN + c1[i]], 1); s1[p] = r1[i]; } }
}

// ---------------- aggregation: sup = 0.8*(D^-1/2 (A+I) D^-1/2 prev) + 0.2*h0 ----------------
// one block per node; z = data branch; mzadd = meta-slot offset (fallback mode)
__global__ void agg_kernel(const _Float16* prevb, const _Float16* h0b, const float* disb,
                           const int* offsb, const int* sr0, const int* sr1,
                           _Float16* supb, int mzadd) {
    const int z = blockIdx.z, mz = z + mzadd;
    const _Float16* prev = prevb + (size_t)z * NN * HID;
    const _Float16* h0 = h0b + (size_t)z * NN * HID;
    _Float16* sup = supb + (size_t)z * NN * HID;
    const float* dis = disb + mz * NN;
    const int* offs = offsb + mz * (NN + 1);
    const int* srow = mz ? sr1 : sr0;
    const int i = blockIdx.x, t = threadIdx.x;
    const size_t base = (size_t)i * HID + t * 2;
    const int e0 = offs[i], e1 = offs[i + 1];
    float a0 = 0.f, a1 = 0.f;
    int e = e0;
    for (; e + 1 < e1; e += 2) {  // unroll-2: two independent gathers in flight
        int ra = srow[e], rb = srow[e + 1];
        float sa = dis[ra], sb = dis[rb];
        h2 va = *(const h2*)&prev[(size_t)ra * HID + t * 2];
        h2 vb = *(const h2*)&prev[(size_t)rb * HID + t * 2];
        a0 += sa * (float)va[0] + sb * (float)vb[0];
        a1 += sa * (float)va[1] + sb * (float)vb[1];
    }
    if (e < e1) {
        int ra = srow[e];
        float sa = dis[ra];
        h2 va = *(const h2*)&prev[(size_t)ra * HID + t * 2];
        a0 += sa * (float)va[0];
        a1 += sa * (float)va[1];
    }
    float si = dis[i];
    h2 pv = *(const h2*)&prev[base];
    h2 hv = *(const h2*)&h0[base];
    float r0 = 0.8f * si * (a0 + si * (float)pv[0]) + 0.2f * (float)hv[0];
    float r1 = 0.8f * si * (a1 + si * (float)pv[1]) + 0.2f * (float)hv[1];
    h2 o; o[0] = (_Float16)r0; o[1] = (_Float16)r1;
    *(h2*)&sup[base] = o;
}

// ---------------- MFMA GEMM (m97 structure, 128x128 tile, BK=64) ----------------
enum { EPI_RELU2 = 0, EPI_BIAS = 1, EPI_GCN = 2 };

struct GArgs {
    const _Float16* A[2];
    const _Float16* BT[2];
    const float* bias[2];
    _Float16* C[2];
    _Float16* C2[2];
    const _Float16* S[2];
    _Float16* P[2];
    int coff[2];
};

template <int EPI>
__global__ __launch_bounds__(256) void gemm_k(GArgs g, int K, int ldc) {
    const int z = blockIdx.z;
    const _Float16* __restrict__ A = g.A[z];
    const _Float16* __restrict__ BT = g.BT[z];
    __shared__ _Float16 lA[8 * 128 * 8];
    __shared__ _Float16 lB[8 * 128 * 8];
    const int tid = threadIdx.x;
    const int wave = tid >> 6, lane = tid & 63;
    const int row0 = blockIdx.x * 128, col0 = blockIdx.y * 128;
    const int wm = wave & 1, wn = wave >> 1;
    f4 acc[4][4] = {};
    const int nk = K >> 6;
    for (int kt = 0; kt < nk; ++kt) {
        const int k0 = kt << 6;
        __syncthreads();
        #pragma unroll
        for (int q = 0; q < 4; ++q) {
            const int c = wave * 4 + q;
            const int k8 = c & 7, rh = c >> 3;
            gload_lds16(A + (size_t)(row0 + rh * 64 + lane) * K + k0 + k8 * 8,
                        &lA[(k8 * 128 + rh * 64) * 8]);
            gload_lds16(BT + (size_t)(col0 + rh * 64 + lane) * K + k0 + k8 * 8,
                        &lB[(k8 * 128 + rh * 64) * 8]);
        }
        __syncthreads();
        #pragma unroll
        for (int s = 0; s < 2; ++s) {
            h8 af[4], bf[4];
            const int kq = s * 4 + (lane >> 4);
            #pragma unroll
            for (int t = 0; t < 4; ++t) {
                af[t] = *(const h8*)&lA[(kq * 128 + wm * 64 + t * 16 + (lane & 15)) * 8];
                bf[t] = *(const h8*)&lB[(kq * 128 + wn * 64 + t * 16 + (lane & 15)) * 8];
            }
            #pragma unroll
            for (int rt = 0; rt < 4; ++rt)
                #pragma unroll
                for (int ct = 0; ct < 4; ++ct)
                    acc[rt][ct] = __builtin_amdgcn_mfma_f32_16x16x32_f16(af[rt], bf[ct], acc[rt][ct], 0, 0, 0);
        }
    }
    // C/D frag mapping: col=lane&15, row=(lane>>4)*4+r (m89-verified)
    #pragma unroll
    for (int rt = 0; rt < 4; ++rt) {
        #pragma unroll
        for (int ct = 0; ct < 4; ++ct) {
            const int col = col0 + wn * 64 + ct * 16 + (lane & 15);
            #pragma unroll
            for (int r = 0; r < 4; ++r) {
                const int row = row0 + wm * 64 + rt * 16 + (lane >> 4) * 4 + r;
                float v = acc[rt][ct][r];
                if (EPI == EPI_RELU2) {
                    v = fmaxf(v + g.bias[z][col], 0.f);
                    g.C[z][(size_t)row * ldc + col] = (_Float16)v;
                    if (g.C2[z]) g.C2[z][(size_t)row * ldc + col] = (_Float16)v;
                } else if (EPI == EPI_BIAS) {
                    g.C[z][(size_t)row * ldc + g.coff[z] + col] = (_Float16)(v + g.bias[z][col]);
                } else {  // EPI_GCN: prev = relu(support + support@W) + prev
                    const size_t idx = (size_t)row * HID + col;
                    float nv = fmaxf((float)g.S[z][idx] + v, 0.f) + (float)g.P[z][idx];
                    g.P[z][idx] = (_Float16)nv;
                }
            }
        }
    }
}

// ---------------- final projection: out[i] = x2[i,:512] . w_o + b_o ----------------
__global__ void final_dot(const _Float16* __restrict__ x2, const float* __restrict__ w,
                          const float* __restrict__ b, float* __restrict__ out) {
    int wave = threadIdx.x >> 6, lane = threadIdx.x & 63;
    int row = blockIdx.x * 4 + wave;
    h8 v = *(const h8*)&x2[(size_t)row * 512 + lane * 8];
    float s = 0.f;
    #pragma unroll
    for (int j = 0; j < 8; ++j) s += (float)v[j] * w[lane * 8 + j];
    #pragma unroll
    for (int off = 32; off > 0; off >>= 1) s += __shfl_down(s, off);
    if (lane == 0) out[row] = s + b[0];
}

// ---------------- workspace plan ----------------
struct WS {
    int *deg, *offs, *cur, *srow0, *srow1;
    float* dis;
    _Float16 *winT, *wsT, *woutT, *fc1T, *fc2T;
    _Float16 *xpad, *h0, *prev, *sup, *xc;
    size_t total;
};

static WS plan(char* base, bool comb) {
    size_t off = 0;
    auto al = [&](size_t n) { off = (off + 255) & ~(size_t)255; size_t o = off; off += n; return base + o; };
    WS w;
    w.deg   = (int*)al(2 * NN * 4);
    w.dis   = (float*)al(2 * NN * 4);
    w.offs  = (int*)al(2 * (NN + 1) * 4);
    w.cur   = (int*)al(2 * NN * 4);
    w.srow0 = (int*)al((size_t)EM * 4);
    w.srow1 = (int*)al((size_t)EP * 4);
    w.winT  = (_Float16*)al(2 * 512 * 128 * 2);
    w.wsT   = (_Float16*)al((size_t)2 * 3 * 512 * 512 * 2);
    w.woutT = (_Float16*)al(2 * 128 * 512 * 2);
    w.fc1T  = (_Float16*)al(1024 * 256 * 2);
    w.fc2T  = (_Float16*)al((size_t)512 * 1024 * 2);
    size_t nb = comb ? 2 : 1;
    w.xpad = (_Float16*)al(nb * NN * 128 * 2);
    w.h0   = (_Float16*)al(nb * NN * HID * 2);   // h0 and prev contiguous: x1 [NN,1024] aliases h0(+prev)
    w.prev = (_Float16*)al(nb * NN * HID * 2);
    w.sup  = (_Float16*)al(nb * NN * HID * 2);
    w.xc   = (_Float16*)al((size_t)NN * 256 * 2);
    w.total = off;
    return w;
}

// ---------------- host orchestration ----------------
extern "C" void kernel_launch(void* const* d_in, const int* in_sizes, int n_in,
                              void* d_out, int out_size, void* d_ws, size_t ws_size,
                              hipStream_t stream) {
    const float* mol_x   = (const float*)d_in[0];
    const int*   mol_ei  = (const int*)d_in[1];
    const float* pro_x   = (const float*)d_in[2];
    const int*   pro_ei  = (const int*)d_in[3];
    const float* win[2]  = {(const float*)d_in[4], (const float*)d_in[9]};
    const float* bin[2]  = {(const float*)d_in[5], (const float*)d_in[10]};
    const float* ws3[2]  = {(const float*)d_in[6], (const float*)d_in[11]};
    const float* wo[2]   = {(const float*)d_in[7], (const float*)d_in[12]};
    const float* bo[2]   = {(const float*)d_in[8], (const float*)d_in[13]};
    const float* w_fc1   = (const float*)d_in[14];
    const float* b_fc1   = (const float*)d_in[15];
    const float* w_fc2   = (const float*)d_in[16];
    const float* b_fc2   = (const float*)d_in[17];
    const float* w_o     = (const float*)d_in[18];
    const float* b_o     = (const float*)d_in[19];
    const int F[2] = {78, 54};

    char* wsb = (char*)d_ws;
    WS w = plan(wsb, true);
    const bool comb = (w.total <= ws_size);
    if (!comb) w = plan(wsb, false);
    const int nz = comb ? 2 : 1;
    const size_t BSTR = comb ? (size_t)NN * HID : 0;       // branch stride for big fp16 arrays
    const size_t XSTR = comb ? (size_t)NN * 128 : 0;

    // --- 1. all weight conversions in one launch ---
    ConvJobs j;
    int nblk = 0, ji = 0;
    auto addjob = [&](const float* s, _Float16* d, int K, int N, int Kp) {
        j.src[ji] = s; j.dst[ji] = d; j.K[ji] = K; j.N[ji] = N; j.Kp[ji] = Kp;
        j.blk0[ji] = nblk; nblk += (N * Kp + 255) / 256; ++ji;
    };
    for (int b = 0; b < 2; ++b) addjob(win[b], w.winT + b * 512 * 128, F[b], 512, 128);
    for (int b = 0; b < 2; ++b)
        for (int l = 0; l < 3; ++l)
            addjob(ws3[b] + (size_t)l * 512 * 512,
                   w.wsT + ((size_t)b * 3 + l) * 512 * 512, 512, 512, 512);
    for (int b = 0; b < 2; ++b) addjob(wo[b], w.woutT + b * 128 * 512, 512, 128, 512);
    addjob(w_fc1, w.fc1T, 256, 1024, 256);
    addjob(w_fc2, w.fc2T, 1024, 512, 1024);
    j.blk0[12] = nblk;
    conv_all<<<nblk, 256, 0, stream>>>(j);

    // --- 2. CSR build, both branches (meta arrays always dual) ---
    init_deg<<<dim3(NN / 256, 1, 2), 256, 0, stream>>>(w.deg);
    count_edges2<<<(EM + EP + 255) / 256, 256, 0, stream>>>(mol_ei + EM, EM, pro_ei + EP, EP, w.deg);
    compute_dis<<<dim3(NN / 256, 1, 2), 256, 0, stream>>>(w.deg, w.dis);
    scan_offsets<<<dim3(1, 1, 2), 1024, 0, stream>>>(w.deg, w.offs, w.cur);
    scatter2<<<(EM + EP + 255) / 256, 256, 0, stream>>>(mol_ei, mol_ei + EM, EM,
                                                        pro_ei, pro_ei + EP, EP,
                                                        w.cur, w.srow0, w.srow1);

    // --- 3. branches ---
    auto branch_chain = [&](int zcount, int b0) {
        // b0 = first branch slot for meta; data slots are z in [0,zcount)
        GArgs g{};
        // input GEMM: h = relu(xpad @ WinT + b); h0 = prev = h
        for (int z = 0; z < zcount; ++z) {
            int b = b0 + z;
            g.A[z] = w.xpad + z * XSTR;
            g.BT[z] = w.winT + b * 512 * 128;
            g.bias[z] = bin[b];
            g.C[z] = w.h0 + z * BSTR;
            g.C2[z] = w.prev + z * BSTR;
        }
        gemm_k<EPI_RELU2><<<dim3(256, 4, zcount), 256, 0, stream>>>(g, 128, HID);
        for (int l = 0; l < 3; ++l) {
            agg_kernel<<<dim3(NN, 1, zcount), 256, 0, stream>>>(
                w.prev, w.h0, w.dis, w.offs, w.srow0, w.srow1, w.sup, b0);
            GArgs gl{};
            for (int z = 0; z < zcount; ++z) {
                int b = b0 + z;
                gl.A[z] = w.sup + z * BSTR;
                gl.BT[z] = w.wsT + ((size_t)b * 3 + l) * 512 * 512;
                gl.S[z] = w.sup + z * BSTR;
                gl.P[z] = w.prev + z * BSTR;
            }
            gemm_k<EPI_GCN><<<dim3(256, 4, zcount), 256, 0, stream>>>(gl, 512, HID);
        }
        GArgs go{};
        for (int z = 0; z < zcount; ++z) {
            int b = b0 + z;
            go.A[z] = w.prev + z * BSTR;
            go.BT[z] = w.woutT + b * 128 * 512;
            go.bias[z] = bo[b];
            go.C[z] = w.xc;
            go.coff[z] = b * 128;
        }
        gemm_k<EPI_BIAS><<<dim3(256, 1, zcount), 256, 0, stream>>>(go, 512, 256);
    };

    if (comb) {
        pad_x2<<<dim3(NN * 128 / 256, 1, 2), 256, 0, stream>>>(mol_x, pro_x, F[0], F[1], w.xpad);
        branch_chain(2, 0);
    } else {
        for (int b = 0; b < 2; ++b) {
            pad_x2<<<dim3(NN * 128 / 256, 1, 1), 256, 0, stream>>>(
                b ? pro_x : mol_x, nullptr, F[b], 0, w.xpad);
            branch_chain(1, b);
        }
    }

    // --- 4. MLP head ---
    _Float16* x1 = w.h0;    // [NN,1024] aliases h0(+prev) block
    _Float16* x2 = w.sup;   // [NN,512]
    GArgs g1{};
    g1.A[0] = w.xc; g1.BT[0] = w.fc1T; g1.bias[0] = b_fc1; g1.C[0] = x1;
    gemm_k<EPI_RELU2><<<dim3(256, 8, 1), 256, 0, stream>>>(g1, 256, 1024);
    GArgs g2{};
    g2.A[0] = x1; g2.BT[0] = w.fc2T; g2.bias[0] = b_fc2; g2.C[0] = x2;
    gemm_k<EPI_RELU2><<<dim3(256, 4, 1), 256, 0, stream>>>(g2, 1024, 512);
    final_dot<<<NN / 4, 256, 0, stream>>>(x2, w_o, b_o, (float*)d_out);
    (void)in_sizes; (void)n_in; (void)out_size; (void)ws_size;
}